// Round 2
// baseline (126.659 us; speedup 1.0000x reference)
//
#include <hip/hip_runtime.h>
#include <hip/hip_bf16.h>

// Problem constants
#define NSEG   4480     // 70 * 64
#define ADIM   64
#define BDIM   16
#define NEDGE  65536
#define UPITCH 1088     // 1024 kernel-derived cols + 64 bias-derived cols
#define LPITCH 68       // LDS row pitch in floats (64 + 4 pad; keeps float4 alignment)

// ---------------------------------------------------------------------------
// proj_kernel: U[a, c] = sum_j atom[a, j] * Brow(c)[j]
//   Brow(c) = kernel + (c&15)*4096 + (c>>4)*64   for c < 1024   (c = i*16 + b)
//           = bias   + (c-1024)*64               for c >= 1024  (bias col i)
// 64x64 tiles, K=64 whole, fp32 vector ALU, LDS j-major for b128 frag loads.
// ~8 us: 624 MFLOP VALU + 19.5 MB U store.
// ---------------------------------------------------------------------------
__global__ __launch_bounds__(256) void proj_kernel(
    const float* __restrict__ atom,
    const float* __restrict__ kern,
    const float* __restrict__ bias,
    float* __restrict__ U)
{
    __shared__ float As[64 * LPITCH];   // As[j][row]
    __shared__ float Bs[64 * LPITCH];   // Bs[j][crow]

    const int t      = threadIdx.x;
    const int a_base = blockIdx.x * 64;
    const int c_base = blockIdx.y * 64;

#pragma unroll
    for (int k = 0; k < 4; ++k) {
        int id  = t + k * 256;
        int row = id >> 4;
        int j0  = (id & 15) * 4;
        float4 v = *(const float4*)(atom + (size_t)(a_base + row) * ADIM + j0);
        As[(j0 + 0) * LPITCH + row] = v.x;
        As[(j0 + 1) * LPITCH + row] = v.y;
        As[(j0 + 2) * LPITCH + row] = v.z;
        As[(j0 + 3) * LPITCH + row] = v.w;
    }
#pragma unroll
    for (int k = 0; k < 4; ++k) {
        int id   = t + k * 256;
        int crow = id >> 4;
        int j0   = (id & 15) * 4;
        int c    = c_base + crow;
        const float* bsrc = (c < 1024)
            ? (kern + (size_t)(c & 15) * 4096 + (size_t)(c >> 4) * 64)
            : (bias + (size_t)(c - 1024) * 64);
        float4 v = *(const float4*)(bsrc + j0);
        Bs[(j0 + 0) * LPITCH + crow] = v.x;
        Bs[(j0 + 1) * LPITCH + crow] = v.y;
        Bs[(j0 + 2) * LPITCH + crow] = v.z;
        Bs[(j0 + 3) * LPITCH + crow] = v.w;
    }
    __syncthreads();

    const int tx = t & 15;
    const int ty = t >> 4;
    const int a0 = ty * 4;
    const int c0 = tx * 4;

    float acc[4][4] = {};
#pragma unroll 8
    for (int j = 0; j < 64; ++j) {
        float4 av = *(const float4*)(As + j * LPITCH + a0);
        float4 bv = *(const float4*)(Bs + j * LPITCH + c0);
        acc[0][0] = fmaf(av.x, bv.x, acc[0][0]);
        acc[0][1] = fmaf(av.x, bv.y, acc[0][1]);
        acc[0][2] = fmaf(av.x, bv.z, acc[0][2]);
        acc[0][3] = fmaf(av.x, bv.w, acc[0][3]);
        acc[1][0] = fmaf(av.y, bv.x, acc[1][0]);
        acc[1][1] = fmaf(av.y, bv.y, acc[1][1]);
        acc[1][2] = fmaf(av.y, bv.z, acc[1][2]);
        acc[1][3] = fmaf(av.y, bv.w, acc[1][3]);
        acc[2][0] = fmaf(av.z, bv.x, acc[2][0]);
        acc[2][1] = fmaf(av.z, bv.y, acc[2][1]);
        acc[2][2] = fmaf(av.z, bv.z, acc[2][2]);
        acc[2][3] = fmaf(av.z, bv.w, acc[2][3]);
        acc[3][0] = fmaf(av.w, bv.x, acc[3][0]);
        acc[3][1] = fmaf(av.w, bv.y, acc[3][1]);
        acc[3][2] = fmaf(av.w, bv.z, acc[3][2]);
        acc[3][3] = fmaf(av.w, bv.w, acc[3][3]);
    }

#pragma unroll
    for (int r = 0; r < 4; ++r) {
        float4 o = make_float4(acc[r][0], acc[r][1], acc[r][2], acc[r][3]);
        *(float4*)(U + (size_t)(a_base + a0 + r) * UPITCH + c_base + c0) = o;
    }
}

// ---------------------------------------------------------------------------
// Counting sort of edges by src atom.
// ---------------------------------------------------------------------------
__global__ __launch_bounds__(256) void hist_kernel(
    const int* __restrict__ pair, int* __restrict__ cnt)
{
    int e = blockIdx.x * 256 + threadIdx.x;
    int src = pair[(size_t)e * 2 + 1];
    atomicAdd(&cnt[src], 1);
}

// One wave. Lane l owns srcs [l*70, l*70+70): exclusive scan into ofs + cur.
__global__ void scan_kernel(const int* __restrict__ cnt,
                            int* __restrict__ ofs, int* __restrict__ cur)
{
    const int lane = threadIdx.x;          // 64 threads
    const int base = lane * 70;
    int sum = 0;
    for (int i = 0; i < 70; ++i) sum += cnt[base + i];
    // exclusive wave scan of per-lane totals
    int pre = sum;
    for (int d = 1; d < 64; d <<= 1) {
        int v = __shfl_up(pre, d, 64);
        if (lane >= d) pre += v;
    }
    pre -= sum;
    int run = pre;
    for (int i = 0; i < 70; ++i) {
        ofs[base + i] = run;
        cur[base + i] = run;
        run += cnt[base + i];
    }
}

__global__ __launch_bounds__(256) void scatter_kernel(
    const int* __restrict__ pair, int* __restrict__ cur, int* __restrict__ idx)
{
    int e = blockIdx.x * 256 + threadIdx.x;
    int src = pair[(size_t)e * 2 + 1];
    int pos = atomicAdd(&cur[src], 1);
    idx[pos] = e;
}

// ---------------------------------------------------------------------------
// edge2_kernel: one wave per SOURCE atom. Load the 4.3 KB U row once into
// registers, then loop over this source's edges: 16 FMA/lane against the
// (broadcast) bond vector, coalesced atomicAdd into the destination row.
// U traffic: 19.5 MB total (read once) instead of 268 MB gathered.
// ---------------------------------------------------------------------------
__global__ __launch_bounds__(256) void edge2_kernel(
    const float* __restrict__ bond,
    const int*   __restrict__ pair,
    const float* __restrict__ U,
    const int*   __restrict__ ofs,
    const int*   __restrict__ cnt,
    const int*   __restrict__ idx,
    float*       __restrict__ out)
{
    const int t    = threadIdx.x;
    const int lane = t & 63;
    const int s    = blockIdx.x * 4 + (t >> 6);   // source atom, 0..4479

    const float4* up = (const float4*)(U + (size_t)s * UPITCH + lane * 16);
    float4 u0 = up[0], u1 = up[1], u2 = up[2], u3 = up[3];
    float ub  = U[(size_t)s * UPITCH + 1024 + lane];

    const int begin = ofs[s];
    const int n     = cnt[s];

    for (int k = 0; k < n; ++k) {
        int e   = idx[begin + k];
        int dst = pair[(size_t)e * 2 + 0];
        const float4* bp = (const float4*)(bond + (size_t)e * BDIM);
        float4 b0 = bp[0], b1 = bp[1], b2 = bp[2], b3 = bp[3];

        float m;
        m  = u0.x * b0.x;
        m  = fmaf(u0.y, b0.y, m);
        m  = fmaf(u0.z, b0.z, m);
        m  = fmaf(u0.w, b0.w, m);
        m  = fmaf(u1.x, b1.x, m);
        m  = fmaf(u1.y, b1.y, m);
        m  = fmaf(u1.z, b1.z, m);
        m  = fmaf(u1.w, b1.w, m);
        m  = fmaf(u2.x, b2.x, m);
        m  = fmaf(u2.y, b2.y, m);
        m  = fmaf(u2.z, b2.z, m);
        m  = fmaf(u2.w, b2.w, m);
        m  = fmaf(u3.x, b3.x, m);
        m  = fmaf(u3.y, b3.y, m);
        m  = fmaf(u3.z, b3.z, m);
        m  = fmaf(u3.w, b3.w, m);
        m += ub;

        atomicAdd(out + (size_t)dst * ADIM + lane, m);
    }
}

extern "C" void kernel_launch(void* const* d_in, const int* in_sizes, int n_in,
                              void* d_out, int out_size, void* d_ws, size_t ws_size,
                              hipStream_t stream) {
    const float* atom = (const float*)d_in[0];   // [4480, 64]  f32
    const float* bond = (const float*)d_in[1];   // [65536, 16] f32
    const int*   pair = (const int*)  d_in[2];   // [65536, 2]  int32
    const float* kern = (const float*)d_in[3];   // [16, 4096]  f32
    const float* bias = (const float*)d_in[4];   // [4096]      f32

    float* out = (float*)d_out;                  // [4480, 64]  f32

    // ws layout (all fp32/int32, 16B-aligned):
    //   U   : 4480*1088 f32 = 19,496,960 B
    //   cnt : 4480 i32
    //   ofs : 4480 i32
    //   cur : 4480 i32
    //   idx : 65536 i32
    char* ws = (char*)d_ws;
    float* U   = (float*)ws;
    int*   cnt = (int*)(ws + (size_t)NSEG * UPITCH * 4);
    int*   ofs = cnt + NSEG;
    int*   cur = ofs + NSEG;
    int*   idx = cur + NSEG;

    hipMemsetAsync(out, 0, (size_t)NSEG * ADIM * sizeof(float), stream);
    hipMemsetAsync(cnt, 0, (size_t)NSEG * sizeof(int), stream);

    dim3 g1(NSEG / 64, UPITCH / 64);             // 70 x 17 tiles
    proj_kernel<<<g1, 256, 0, stream>>>(atom, kern, bias, U);

    hist_kernel<<<NEDGE / 256, 256, 0, stream>>>(pair, cnt);
    scan_kernel<<<1, 64, 0, stream>>>(cnt, ofs, cur);
    scatter_kernel<<<NEDGE / 256, 256, 0, stream>>>(pair, cur, idx);

    edge2_kernel<<<NSEG / 4, 256, 0, stream>>>(bond, pair, U, ofs, cnt, idx, out);
}

// Round 3
// 99.416 us; speedup vs baseline: 1.2740x; 1.2740x over previous
//
#include <hip/hip_runtime.h>
#include <hip/hip_bf16.h>

// Problem constants
#define NSEG   4480     // 70 * 64
#define ADIM   64
#define BDIM   16
#define NEDGE  65536
#define UPITCH 1088     // bf16 elements per U row: 1024 kernel-cols + 64 bias-cols (2176 B)
#define LPITCH 68       // LDS row pitch in floats (64 + 4 pad)

__device__ __forceinline__ float bf2f(unsigned int bits_hi16) {
    union { unsigned int i; float f; } c; c.i = bits_hi16; return c.f;
}
__device__ __forceinline__ unsigned short f2bf(float f) {
    union { float f; unsigned int i; } c; c.f = f;
    unsigned int x = c.i;
    x += 0x7fffu + ((x >> 16) & 1u);   // round-to-nearest-even
    return (unsigned short)(x >> 16);
}

// ---------------------------------------------------------------------------
// proj_kernel: U[a, c] = sum_j atom[a,j] * Brow(c)[j], stored bf16.
//   Brow(c) = kernel + (c&15)*4096 + (c>>4)*64   for c < 1024   (c = i*16+b)
//           = bias   + (c-1024)*64               for c >= 1024  (bias col i)
// 64x64 tiles, K=64 whole, fp32 vector ALU, LDS j-major for b128 frag loads.
// Also zeroes `out` (first 70 blocks) — stream order makes this safe for the
// edge kernel's atomics, so no separate hipMemsetAsync op is needed.
// ---------------------------------------------------------------------------
__global__ __launch_bounds__(256) void proj_kernel(
    const float* __restrict__ atom,
    const float* __restrict__ kern,
    const float* __restrict__ bias,
    unsigned short* __restrict__ U,
    float* __restrict__ out)
{
    __shared__ float As[64 * LPITCH];   // As[j][row]
    __shared__ float Bs[64 * LPITCH];   // Bs[j][crow]

    const int t      = threadIdx.x;
    const int bx     = blockIdx.x;      // 0..69  atom tile
    const int by     = blockIdx.y;      // 0..16  col tile (16 = bias)
    const int a_base = bx * 64;
    const int c_base = by * 64;

    // zero out[] (4480*64 f32 = 17920 float4) using the by==0 blocks
    {
        int gid = by * 70 * 256 + bx * 256 + t;   // linear over (by,bx,t)
        if (gid < NSEG * ADIM / 4) {
            ((float4*)out)[gid] = make_float4(0.f, 0.f, 0.f, 0.f);
        }
    }

#pragma unroll
    for (int k = 0; k < 4; ++k) {
        int id  = t + k * 256;
        int row = id >> 4;
        int j0  = (id & 15) * 4;
        float4 v = *(const float4*)(atom + (size_t)(a_base + row) * ADIM + j0);
        As[(j0 + 0) * LPITCH + row] = v.x;
        As[(j0 + 1) * LPITCH + row] = v.y;
        As[(j0 + 2) * LPITCH + row] = v.z;
        As[(j0 + 3) * LPITCH + row] = v.w;
    }
#pragma unroll
    for (int k = 0; k < 4; ++k) {
        int id   = t + k * 256;
        int crow = id >> 4;
        int j0   = (id & 15) * 4;
        int c    = c_base + crow;
        const float* bsrc = (c < 1024)
            ? (kern + (size_t)(c & 15) * 4096 + (size_t)(c >> 4) * 64)
            : (bias + (size_t)(c - 1024) * 64);
        float4 v = *(const float4*)(bsrc + j0);
        Bs[(j0 + 0) * LPITCH + crow] = v.x;
        Bs[(j0 + 1) * LPITCH + crow] = v.y;
        Bs[(j0 + 2) * LPITCH + crow] = v.z;
        Bs[(j0 + 3) * LPITCH + crow] = v.w;
    }
    __syncthreads();

    const int tx = t & 15;
    const int ty = t >> 4;
    const int a0 = ty * 4;
    const int c0 = tx * 4;

    float acc[4][4] = {};
#pragma unroll 8
    for (int j = 0; j < 64; ++j) {
        float4 av = *(const float4*)(As + j * LPITCH + a0);
        float4 bv = *(const float4*)(Bs + j * LPITCH + c0);
        acc[0][0] = fmaf(av.x, bv.x, acc[0][0]);
        acc[0][1] = fmaf(av.x, bv.y, acc[0][1]);
        acc[0][2] = fmaf(av.x, bv.z, acc[0][2]);
        acc[0][3] = fmaf(av.x, bv.w, acc[0][3]);
        acc[1][0] = fmaf(av.y, bv.x, acc[1][0]);
        acc[1][1] = fmaf(av.y, bv.y, acc[1][1]);
        acc[1][2] = fmaf(av.y, bv.z, acc[1][2]);
        acc[1][3] = fmaf(av.y, bv.w, acc[1][3]);
        acc[2][0] = fmaf(av.z, bv.x, acc[2][0]);
        acc[2][1] = fmaf(av.z, bv.y, acc[2][1]);
        acc[2][2] = fmaf(av.z, bv.z, acc[2][2]);
        acc[2][3] = fmaf(av.z, bv.w, acc[2][3]);
        acc[3][0] = fmaf(av.w, bv.x, acc[3][0]);
        acc[3][1] = fmaf(av.w, bv.y, acc[3][1]);
        acc[3][2] = fmaf(av.w, bv.z, acc[3][2]);
        acc[3][3] = fmaf(av.w, bv.w, acc[3][3]);
    }

#pragma unroll
    for (int r = 0; r < 4; ++r) {
        ushort4 o;
        o.x = f2bf(acc[r][0]);
        o.y = f2bf(acc[r][1]);
        o.z = f2bf(acc[r][2]);
        o.w = f2bf(acc[r][3]);
        *(ushort4*)(U + (size_t)(a_base + a0 + r) * UPITCH + c_base + c0) = o;
    }
}

// ---------------------------------------------------------------------------
// edge_kernel: one wave per edge; lane i computes msg[e,i].
//   msg[e,i] = sum_b bond[e,b] * U[src, i*16+b]  +  U[src, 1024+i]
// Lane i reads its 16 bf16 weights as 2 contiguous uint4 (wave streams the
// whole 2.1 KB row coalesced; U is L3/L2-resident at 9.7 MB). Scatter via
// coalesced per-row atomicAdd.
// ---------------------------------------------------------------------------
__global__ __launch_bounds__(256) void edge_kernel(
    const float*          __restrict__ bond,
    const int*            __restrict__ pair,
    const unsigned short* __restrict__ U,
    float*                __restrict__ out)
{
    const int t    = threadIdx.x;
    const int lane = t & 63;
    const int e    = blockIdx.x * 4 + (t >> 6);

    const int dst = pair[(size_t)e * 2 + 0];
    const int src = pair[(size_t)e * 2 + 1];

    const unsigned short* urow = U + (size_t)src * UPITCH;
    const uint4* up = (const uint4*)(urow + lane * 16);
    uint4 w0 = up[0];
    uint4 w1 = up[1];

    const float4* bp = (const float4*)(bond + (size_t)e * BDIM);
    float4 b0 = bp[0], b1 = bp[1], b2 = bp[2], b3 = bp[3];
    float b[16] = { b0.x, b0.y, b0.z, b0.w,  b1.x, b1.y, b1.z, b1.w,
                    b2.x, b2.y, b2.z, b2.w,  b3.x, b3.y, b3.z, b3.w };

    unsigned int w[8] = { w0.x, w0.y, w0.z, w0.w, w1.x, w1.y, w1.z, w1.w };

    float m = 0.f;
#pragma unroll
    for (int k = 0; k < 8; ++k) {
        float lo = bf2f(w[k] << 16);           // element b = 2k   (low ushort)
        float hi = bf2f(w[k] & 0xffff0000u);   // element b = 2k+1 (high ushort)
        m = fmaf(lo, b[2 * k],     m);
        m = fmaf(hi, b[2 * k + 1], m);
    }

    // bias contribution: U col 1024 + i
    m += bf2f(((unsigned int)urow[1024 + lane]) << 16);

    atomicAdd(out + (size_t)dst * ADIM + lane, m);
}

extern "C" void kernel_launch(void* const* d_in, const int* in_sizes, int n_in,
                              void* d_out, int out_size, void* d_ws, size_t ws_size,
                              hipStream_t stream) {
    const float* atom = (const float*)d_in[0];   // [4480, 64]  f32
    const float* bond = (const float*)d_in[1];   // [65536, 16] f32
    const int*   pair = (const int*)  d_in[2];   // [65536, 2]  int32
    const float* kern = (const float*)d_in[3];   // [16, 4096]  f32
    const float* bias = (const float*)d_in[4];   // [4096]      f32

    float* out = (float*)d_out;                  // [4480, 64]  f32
    unsigned short* U = (unsigned short*)d_ws;   // [4480, 1088] bf16 = 9.75 MB

    dim3 g1(NSEG / 64, UPITCH / 64);             // 70 x 17 tiles; by==0 slice zeroes out[]
    proj_kernel<<<g1, 256, 0, stream>>>(atom, kern, bias, U, out);

    edge_kernel<<<NEDGE / 4, 256, 0, stream>>>(bond, pair, U, out);
}